// Round 12
// baseline (268.296 us; speedup 1.0000x reference)
//
#include <hip/hip_runtime.h>

#define KE_CONST 14.3996454784255f

#define P2_SHIFT 15
#define P2_CHUNK 32768            // 128 KB LDS accumulator per chunk
#define SCAN_B2  64               // blocks per chunk
#define SCAN_THR 1024             // 16 waves/block, 1 block/CU (132 KB LDS)
#define MAXC     4
#define MAXE     16               // pair table up to 256 entries (4 KB LDS)

// ---------------- prep A: per-node element id (argmax over attrs) ----------------
__global__ void zbl_prep_elem(const float* __restrict__ node_attrs,
                              unsigned char* __restrict__ elem,
                              int n_nodes, int n_elem) {
    int n = blockIdx.x * blockDim.x + threadIdx.x;
    if (n >= n_nodes) return;
    const float* row = node_attrs + (size_t)n * n_elem;
    float best = row[0];
    int bi = 0;
    for (int i = 1; i < n_elem; ++i) {
        float v = row[i];
        if (v > best) { best = v; bi = i; }
    }
    elem[n] = (unsigned char)bi;
}

// ---------------- prep B: n_elem^2 pair table ----------------
// pair_tab[eu*n_elem+ev] = { 1/a, 0.5*KE*Zu*Zv, rmax, 1/rmax }
__global__ void zbl_prep_pairs(const int* __restrict__ atomic_numbers,
                               const float* __restrict__ covalent_radii,
                               float4* __restrict__ pair_tab,
                               int n_elem) {
    int t = threadIdx.x;
    int np = n_elem * n_elem;
    if (t >= np) return;
    int eu = t / n_elem;
    int ev = t - eu * n_elem;
    int Zu = atomic_numbers[eu];
    int Zv = atomic_numbers[ev];
    float zu = (float)Zu, zv = (float)Zv;
    float inv_a = (__powf(zu, 0.3f) + __powf(zv, 0.3f)) * (1.0f / (0.4543f * 0.529f));
    float kezz  = 0.5f * KE_CONST * zu * zv;
    float rmax  = covalent_radii[Zu] + covalent_radii[Zv];
    pair_tab[t] = make_float4(inv_a, kezz, rmax, 1.0f / rmax);
}

// ---------------- per-edge value from pair-table entry (full f32) ----------------
__device__ __forceinline__ float edge_val(float xv, const float4& p) {
    float t = xv * p.x;
    float phi = 0.1818f  * __expf(-3.2f    * t)
              + 0.5099f  * __expf(-0.9423f * t)
              + 0.2802f  * __expf(-0.4028f * t)
              + 0.02817f * __expf(-0.2016f * t);
    float rr = xv * p.w;
    float r2 = rr * rr;
    float r6 = r2 * r2 * r2;
    float env = 1.0f - 28.0f * r6 + 48.0f * r6 * rr - 21.0f * r6 * r2;
    return p.y * phi / xv * env;     // caller applies (xv < rmax) predicate
}

// ---------------- fused pass: stream edges, compute, LDS-accumulate in-chunk ----------------
// Replaces dense+scan: deletes the 25.6 MB packed write + 102 MB packed re-read.
// Math is branchless x4-redundant (cheap since pair-table); gathers are 2 bytes
// from the hot 100 KB elem table; atomics predicated on (in-chunk && x < rmax).
__global__ __launch_bounds__(SCAN_THR)
void zbl_fused(const float* __restrict__ x,
               const int* __restrict__ ei,
               const unsigned char* __restrict__ elem,
               const float4* __restrict__ pair_tab,
               float* __restrict__ partial,
               int n_edges, int n_elem) {
    unsigned c = blockIdx.x >> 6;            // SCAN_B2 = 64
    int      j = blockIdx.x & (SCAN_B2 - 1);

    __shared__ __align__(16) float acc[P2_CHUNK];
    __shared__ float4 pt[MAXE * MAXE];
    int np = n_elem * n_elem;
    for (int i = threadIdx.x; i < np; i += SCAN_THR) pt[i] = pair_tab[i];
    for (int i = threadIdx.x * 4; i < P2_CHUNK; i += SCAN_THR * 4)
        *(float4*)&acc[i] = make_float4(0.f, 0.f, 0.f, 0.f);
    __syncthreads();

    const int* __restrict__ rcv = ei + n_edges;
    long long e0 = (((long long)j * n_edges) / SCAN_B2) & ~3LL;
    long long e1 = (j == SCAN_B2 - 1) ? (long long)n_edges
                                      : ((((long long)(j + 1) * n_edges) / SCAN_B2) & ~3LL);
    long long vend = e1 & ~3LL;

    for (long long b = e0 + (long long)threadIdx.x * 4; b + 4 <= vend;
         b += (long long)SCAN_THR * 4) {
        int4   r4 = *(const int4*)(rcv + b);
        int4   s4 = *(const int4*)(ei + b);
        float4 x4 = *(const float4*)(x + b);
        // 8 independent byte gathers, issued up front
        unsigned es0 = elem[s4.x], es1 = elem[s4.y], es2 = elem[s4.z], es3 = elem[s4.w];
        unsigned er0 = elem[r4.x], er1 = elem[r4.y], er2 = elem[r4.z], er3 = elem[r4.w];
        float4 p0 = pt[es0 * n_elem + er0];
        float4 p1 = pt[es1 * n_elem + er1];
        float4 p2 = pt[es2 * n_elem + er2];
        float4 p3 = pt[es3 * n_elem + er3];
        float v0 = edge_val(x4.x, p0);
        float v1 = edge_val(x4.y, p1);
        float v2 = edge_val(x4.z, p2);
        float v3 = edge_val(x4.w, p3);
        if (((unsigned)(r4.x >> P2_SHIFT) == c) & (x4.x < p0.z))
            atomicAdd(&acc[r4.x & (P2_CHUNK - 1)], v0);
        if (((unsigned)(r4.y >> P2_SHIFT) == c) & (x4.y < p1.z))
            atomicAdd(&acc[r4.y & (P2_CHUNK - 1)], v1);
        if (((unsigned)(r4.z >> P2_SHIFT) == c) & (x4.z < p2.z))
            atomicAdd(&acc[r4.z & (P2_CHUNK - 1)], v2);
        if (((unsigned)(r4.w >> P2_SHIFT) == c) & (x4.w < p3.z))
            atomicAdd(&acc[r4.w & (P2_CHUNK - 1)], v3);
    }
    // scalar tail (last block only, n_edges % 4 != 0)
    for (long long e = vend + threadIdx.x; e < e1; e += SCAN_THR) {
        int r = rcv[e];
        if ((unsigned)(r >> P2_SHIFT) != c) continue;
        float4 p = pt[elem[ei[e]] * n_elem + elem[r]];
        float xv = x[e];
        if (xv < p.z) atomicAdd(&acc[r & (P2_CHUNK - 1)], edge_val(xv, p));
    }

    __syncthreads();
    float* pp = partial + (size_t)blockIdx.x * P2_CHUNK;
    for (int i = threadIdx.x * 4; i < P2_CHUNK; i += SCAN_THR * 4)
        *(float4*)(pp + i) = *(const float4*)&acc[i];
}

// ---------------- reduce SCAN_B2 partials per node, overwrite out ----------------
__global__ void zbl_reduce(const float* __restrict__ partial,
                           float* __restrict__ out,
                           int n_nodes) {
    int i = blockIdx.x * blockDim.x + threadIdx.x;
    if (i >= n_nodes) return;
    int c  = i >> P2_SHIFT;
    int li = i & (P2_CHUNK - 1);
    const float* p = partial + ((size_t)c * SCAN_B2) * P2_CHUNK + li;
    float s0 = 0.f, s1 = 0.f, s2 = 0.f, s3 = 0.f;
    #pragma unroll
    for (int j = 0; j < SCAN_B2; j += 4) {
        s0 += p[(size_t)(j + 0) * P2_CHUNK];
        s1 += p[(size_t)(j + 1) * P2_CHUNK];
        s2 += p[(size_t)(j + 2) * P2_CHUNK];
        s3 += p[(size_t)(j + 3) * P2_CHUNK];
    }
    out[i] = (s0 + s1) + (s2 + s3);
}

// ================= fallback path: node float4 table + direct device atomics =================
__global__ void zbl_node_prep(const float* __restrict__ node_attrs,
                              const int* __restrict__ atomic_numbers,
                              const float* __restrict__ covalent_radii,
                              float4* __restrict__ node_data,
                              float* __restrict__ out_zero,
                              int n_nodes, int n_elem) {
    int n = blockIdx.x * blockDim.x + threadIdx.x;
    if (n >= n_nodes) return;
    const float* row = node_attrs + (size_t)n * n_elem;
    float best = row[0];
    int bi = 0;
    for (int i = 1; i < n_elem; ++i) {
        float v = row[i];
        if (v > best) { best = v; bi = i; }
    }
    int Z = atomic_numbers[bi];
    float zf = (float)Z;
    node_data[n] = make_float4(zf, __powf(zf, 0.3f), covalent_radii[Z], 0.0f);
    out_zero[n] = 0.0f;
}

__global__ void zbl_edge_atomic(const float* __restrict__ x,
                                const int* __restrict__ edge_index,
                                const float4* __restrict__ node_data,
                                float* __restrict__ out,
                                int n_edges) {
    int e = blockIdx.x * blockDim.x + threadIdx.x;
    if (e >= n_edges) return;
    int snd = edge_index[e];
    int r = edge_index[n_edges + e];
    float xv = x[e];
    float4 du = node_data[snd];
    float4 dv = node_data[r];
    float rmax = du.z + dv.z;
    if (xv >= rmax) return;
    const float inv_a_pref = 1.0f / (0.4543f * 0.529f);
    float t = xv * (du.y + dv.y) * inv_a_pref;
    float phi = 0.1818f  * __expf(-3.2f    * t)
              + 0.5099f  * __expf(-0.9423f * t)
              + 0.2802f  * __expf(-0.4028f * t)
              + 0.02817f * __expf(-0.2016f * t);
    float v = KE_CONST * du.x * dv.x * phi / xv;
    float rr = xv / rmax;
    float r2 = rr * rr;
    float r6 = r2 * r2 * r2;
    float env = 1.0f - 28.0f * r6 + 48.0f * r6 * rr - 21.0f * r6 * r2;
    atomicAdd(&out[r], 0.5f * v * env);
}

extern "C" void kernel_launch(void* const* d_in, const int* in_sizes, int n_in,
                              void* d_out, int out_size, void* d_ws, size_t ws_size,
                              hipStream_t stream) {
    const float* x              = (const float*)d_in[0];
    const float* node_attrs     = (const float*)d_in[1];
    const int*   edge_index     = (const int*)d_in[2];
    const int*   atomic_numbers = (const int*)d_in[3];
    const float* covalent_radii = (const float*)d_in[4];
    float* out = (float*)d_out;

    int n_edges = in_sizes[0];
    int n_elem  = in_sizes[3];
    int n_nodes = in_sizes[1] / n_elem;

    int C = (n_nodes + P2_CHUNK - 1) >> P2_SHIFT;
    size_t elem_bytes = (((size_t)n_nodes) + 255) & ~(size_t)255;
    size_t pair_bytes = ((size_t)MAXE * MAXE * sizeof(float4) + 255) & ~(size_t)255;
    size_t part_bytes = (size_t)C * SCAN_B2 * P2_CHUNK * sizeof(float);
    bool fast = (C >= 1) && (C <= MAXC) && (n_nodes <= (1 << 17)) &&
                (n_elem >= 1) && (n_elem <= MAXE) &&
                (ws_size >= elem_bytes + pair_bytes + part_bytes);

    if (fast) {
        unsigned char* elem     = (unsigned char*)d_ws;
        float4*        pair_tab = (float4*)((char*)d_ws + elem_bytes);
        float*         part     = (float*)((char*)d_ws + elem_bytes + pair_bytes);

        zbl_prep_elem<<<(n_nodes + 255) / 256, 256, 0, stream>>>(
            node_attrs, elem, n_nodes, n_elem);
        zbl_prep_pairs<<<1, 256, 0, stream>>>(
            atomic_numbers, covalent_radii, pair_tab, n_elem);

        zbl_fused<<<C * SCAN_B2, SCAN_THR, 0, stream>>>(
            x, edge_index, elem, pair_tab, part, n_edges, n_elem);

        zbl_reduce<<<(n_nodes + 255) / 256, 256, 0, stream>>>(part, out, n_nodes);
        return;
    }

    // fallback: node table + plain device atomics
    float4* node_data = (float4*)d_ws;
    zbl_node_prep<<<(n_nodes + 255) / 256, 256, 0, stream>>>(
        node_attrs, atomic_numbers, covalent_radii, node_data,
        out, n_nodes, n_elem);
    zbl_edge_atomic<<<(n_edges + 255) / 256, 256, 0, stream>>>(
        x, edge_index, node_data, out, n_edges);
}

// Round 13
// 168.610 us; speedup vs baseline: 1.5912x; 1.5912x over previous
//
#include <hip/hip_runtime.h>

#define KE_CONST 14.3996454784255f

#define P2_SHIFT 15
#define P2_CHUNK 32768            // 128 KB LDS accumulator per chunk (scan)
#define SCAN_B2  64               // scan blocks per chunk
#define SCAN_THR 1024
#define MAXC     4
#define MAXE     16               // pair table up to 256 entries (4 KB LDS)
#define ELEM_CAP 131072           // 128 KB LDS elem table cap (dense)
#define DN_THR   1024
#define DN_BLOCKS 256

// ---------------- prep A: per-node element id (argmax over attrs) ----------------
__global__ void zbl_prep_elem(const float* __restrict__ node_attrs,
                              unsigned char* __restrict__ elem,
                              int n_nodes, int n_elem) {
    int n = blockIdx.x * blockDim.x + threadIdx.x;
    if (n >= n_nodes) return;
    const float* row = node_attrs + (size_t)n * n_elem;
    float best = row[0];
    int bi = 0;
    for (int i = 1; i < n_elem; ++i) {
        float v = row[i];
        if (v > best) { best = v; bi = i; }
    }
    elem[n] = (unsigned char)bi;
}

// ---------------- prep B: n_elem^2 pair table ----------------
// pair_tab[eu*n_elem+ev] = { 1/a, 0.5*KE*Zu*Zv, rmax, 1/rmax }
__global__ void zbl_prep_pairs(const int* __restrict__ atomic_numbers,
                               const float* __restrict__ covalent_radii,
                               float4* __restrict__ pair_tab,
                               int n_elem) {
    int t = threadIdx.x;
    int np = n_elem * n_elem;
    if (t >= np) return;
    int eu = t / n_elem;
    int ev = t - eu * n_elem;
    int Zu = atomic_numbers[eu];
    int Zv = atomic_numbers[ev];
    float zu = (float)Zu, zv = (float)Zv;
    float inv_a = (__powf(zu, 0.3f) + __powf(zv, 0.3f)) * (1.0f / (0.4543f * 0.529f));
    float kezz  = 0.5f * KE_CONST * zu * zv;
    float rmax  = covalent_radii[Zu] + covalent_radii[Zv];
    pair_tab[t] = make_float4(inv_a, kezz, rmax, 1.0f / rmax);
}

// ---------------- per-edge e8m7 value from pair-table entry ----------------
__device__ __forceinline__ unsigned enc_val_p(float xv, const float4& p) {
    float t = xv * p.x;
    float phi = 0.1818f  * __expf(-3.2f    * t)
              + 0.5099f  * __expf(-0.9423f * t)
              + 0.2802f  * __expf(-0.4028f * t)
              + 0.02817f * __expf(-0.2016f * t);
    float rr = xv * p.w;
    float r2 = rr * rr;
    float r6 = r2 * r2 * r2;
    float env = 1.0f - 28.0f * r6 + 48.0f * r6 * rr - 21.0f * r6 * r2;
    float val = fmaxf(p.y * phi / xv * env, 0.0f);     // clamp r->1 cancellation negatives
    unsigned e = (__float_as_uint(val) + 0x8000u) >> 16;
    if (e > 0x7FFFu) e = 0x7FFFu;
    return (xv < p.z) ? e : 0u;
}

// ---------------- pass 1: dense streaming compute -> packed u32 per edge ----------------
// Whole elem table staged in LDS (128 KB): per-edge gathers become ds_read_u8
// (~120 cyc, hidden by 16 waves) instead of L2 round-trips (~200-400 cyc) that
// pinned dense at 57-76 us across rounds 8-11 (compiler refuses gather MLP).
__global__ __launch_bounds__(DN_THR)
void zbl_dense_lds(const float* __restrict__ x,
                   const int* __restrict__ ei,
                   const unsigned char* __restrict__ elem_g,
                   const float4* __restrict__ pair_tab,
                   unsigned* __restrict__ packed,
                   int n_edges, int n_elem, int n_nodes) {
    __shared__ __align__(16) unsigned char elem[ELEM_CAP];
    __shared__ float4 pt[MAXE * MAXE];

    int np = n_elem * n_elem;
    for (int i = threadIdx.x; i < np; i += DN_THR) pt[i] = pair_tab[i];
    int nwords = (n_nodes + 15) >> 4;                 // uint4 copies
    const uint4* eg4 = (const uint4*)elem_g;
    uint4* el4 = (uint4*)elem;
    for (int i = threadIdx.x; i < nwords; i += DN_THR) el4[i] = eg4[i];
    __syncthreads();

    long long e0 = (((long long)blockIdx.x * n_edges) / DN_BLOCKS) & ~3LL;
    long long e1 = (blockIdx.x == DN_BLOCKS - 1)
                     ? (long long)n_edges
                     : ((((long long)(blockIdx.x + 1) * n_edges) / DN_BLOCKS) & ~3LL);
    long long vend = e1 & ~3LL;

    for (long long b = e0 + (long long)threadIdx.x * 4; b + 4 <= vend;
         b += (long long)DN_THR * 4) {
        int4   s4 = *(const int4*)(ei + b);
        int4   r4 = *(const int4*)(ei + n_edges + b);
        float4 x4 = *(const float4*)(x + b);
        unsigned es0 = elem[s4.x], es1 = elem[s4.y], es2 = elem[s4.z], es3 = elem[s4.w];
        unsigned er0 = elem[r4.x], er1 = elem[r4.y], er2 = elem[r4.z], er3 = elem[r4.w];
        float4 p0 = pt[es0 * n_elem + er0];
        float4 p1 = pt[es1 * n_elem + er1];
        float4 p2 = pt[es2 * n_elem + er2];
        float4 p3 = pt[es3 * n_elem + er3];
        uint4 o;
        o.x = ((unsigned)r4.x << 15) | enc_val_p(x4.x, p0);
        o.y = ((unsigned)r4.y << 15) | enc_val_p(x4.y, p1);
        o.z = ((unsigned)r4.z << 15) | enc_val_p(x4.z, p2);
        o.w = ((unsigned)r4.w << 15) | enc_val_p(x4.w, p3);
        *(uint4*)(packed + b) = o;                    // lane-contiguous 1 KB burst
    }
    // scalar tail (last block only)
    for (long long e = vend + threadIdx.x; e < e1; e += DN_THR) {
        int r = ei[n_edges + e];
        float4 p = pt[elem[ei[e]] * n_elem + elem[r]];
        packed[e] = ((unsigned)r << 15) | enc_val_p(x[e], p);
    }
}

// ---------------- pass 2: chunked scan of packed records, LDS accumulate ----------------
__global__ __launch_bounds__(SCAN_THR)
void zbl_scan(const unsigned* __restrict__ packed,
              float* __restrict__ partial,
              int n_edges) {
    unsigned c = blockIdx.x >> 6;            // SCAN_B2 = 64
    int      j = blockIdx.x & (SCAN_B2 - 1);

    __shared__ __align__(16) float acc[P2_CHUNK];
    for (int i = threadIdx.x * 4; i < P2_CHUNK; i += SCAN_THR * 4)
        *(float4*)&acc[i] = make_float4(0.f, 0.f, 0.f, 0.f);
    __syncthreads();

    long long e0 = (((long long)j * n_edges) / SCAN_B2) & ~3LL;
    long long e1 = (j == SCAN_B2 - 1) ? (long long)n_edges
                                      : ((((long long)(j + 1) * n_edges) / SCAN_B2) & ~3LL);
    long long vend = e1 & ~3LL;

    for (long long b = e0 + (long long)threadIdx.x * 4; b + 4 <= vend;
         b += (long long)SCAN_THR * 4) {
        uint4 p = *(const uint4*)(packed + b);
        if ((p.x >> 30) == c) atomicAdd(&acc[(p.x >> 15) & (P2_CHUNK - 1)],
                                        __uint_as_float((p.x & 0x7FFFu) << 16));
        if ((p.y >> 30) == c) atomicAdd(&acc[(p.y >> 15) & (P2_CHUNK - 1)],
                                        __uint_as_float((p.y & 0x7FFFu) << 16));
        if ((p.z >> 30) == c) atomicAdd(&acc[(p.z >> 15) & (P2_CHUNK - 1)],
                                        __uint_as_float((p.z & 0x7FFFu) << 16));
        if ((p.w >> 30) == c) atomicAdd(&acc[(p.w >> 15) & (P2_CHUNK - 1)],
                                        __uint_as_float((p.w & 0x7FFFu) << 16));
    }
    for (long long e = vend + threadIdx.x; e < e1; e += SCAN_THR) {
        unsigned w = packed[e];
        if ((w >> 30) == c) atomicAdd(&acc[(w >> 15) & (P2_CHUNK - 1)],
                                      __uint_as_float((w & 0x7FFFu) << 16));
    }

    __syncthreads();
    float* pp = partial + (size_t)blockIdx.x * P2_CHUNK;
    for (int i = threadIdx.x * 4; i < P2_CHUNK; i += SCAN_THR * 4)
        *(float4*)(pp + i) = *(const float4*)&acc[i];
}

// ---------------- pass 3: reduce SCAN_B2 partials per node, overwrite out ----------------
__global__ void zbl_reduce(const float* __restrict__ partial,
                           float* __restrict__ out,
                           int n_nodes) {
    int i = blockIdx.x * blockDim.x + threadIdx.x;
    if (i >= n_nodes) return;
    int c  = i >> P2_SHIFT;
    int li = i & (P2_CHUNK - 1);
    const float* p = partial + ((size_t)c * SCAN_B2) * P2_CHUNK + li;
    float s0 = 0.f, s1 = 0.f, s2 = 0.f, s3 = 0.f;
    #pragma unroll
    for (int j = 0; j < SCAN_B2; j += 4) {
        s0 += p[(size_t)(j + 0) * P2_CHUNK];
        s1 += p[(size_t)(j + 1) * P2_CHUNK];
        s2 += p[(size_t)(j + 2) * P2_CHUNK];
        s3 += p[(size_t)(j + 3) * P2_CHUNK];
    }
    out[i] = (s0 + s1) + (s2 + s3);
}

// ================= fallback path: node float4 table + direct device atomics =================
__global__ void zbl_node_prep(const float* __restrict__ node_attrs,
                              const int* __restrict__ atomic_numbers,
                              const float* __restrict__ covalent_radii,
                              float4* __restrict__ node_data,
                              float* __restrict__ out_zero,
                              int n_nodes, int n_elem) {
    int n = blockIdx.x * blockDim.x + threadIdx.x;
    if (n >= n_nodes) return;
    const float* row = node_attrs + (size_t)n * n_elem;
    float best = row[0];
    int bi = 0;
    for (int i = 1; i < n_elem; ++i) {
        float v = row[i];
        if (v > best) { best = v; bi = i; }
    }
    int Z = atomic_numbers[bi];
    float zf = (float)Z;
    node_data[n] = make_float4(zf, __powf(zf, 0.3f), covalent_radii[Z], 0.0f);
    out_zero[n] = 0.0f;
}

__global__ void zbl_edge_atomic(const float* __restrict__ x,
                                const int* __restrict__ edge_index,
                                const float4* __restrict__ node_data,
                                float* __restrict__ out,
                                int n_edges) {
    int e = blockIdx.x * blockDim.x + threadIdx.x;
    if (e >= n_edges) return;
    int snd = edge_index[e];
    int r = edge_index[n_edges + e];
    float xv = x[e];
    float4 du = node_data[snd];
    float4 dv = node_data[r];
    float rmax = du.z + dv.z;
    if (xv >= rmax) return;
    const float inv_a_pref = 1.0f / (0.4543f * 0.529f);
    float t = xv * (du.y + dv.y) * inv_a_pref;
    float phi = 0.1818f  * __expf(-3.2f    * t)
              + 0.5099f  * __expf(-0.9423f * t)
              + 0.2802f  * __expf(-0.4028f * t)
              + 0.02817f * __expf(-0.2016f * t);
    float v = KE_CONST * du.x * dv.x * phi / xv;
    float rr = xv / rmax;
    float r2 = rr * rr;
    float r6 = r2 * r2 * r2;
    float env = 1.0f - 28.0f * r6 + 48.0f * r6 * rr - 21.0f * r6 * r2;
    atomicAdd(&out[r], 0.5f * v * env);
}

extern "C" void kernel_launch(void* const* d_in, const int* in_sizes, int n_in,
                              void* d_out, int out_size, void* d_ws, size_t ws_size,
                              hipStream_t stream) {
    const float* x              = (const float*)d_in[0];
    const float* node_attrs     = (const float*)d_in[1];
    const int*   edge_index     = (const int*)d_in[2];
    const int*   atomic_numbers = (const int*)d_in[3];
    const float* covalent_radii = (const float*)d_in[4];
    float* out = (float*)d_out;

    int n_edges = in_sizes[0];
    int n_elem  = in_sizes[3];
    int n_nodes = in_sizes[1] / n_elem;

    int C = (n_nodes + P2_CHUNK - 1) >> P2_SHIFT;
    size_t elem_bytes   = (((size_t)n_nodes) + 255) & ~(size_t)255;
    size_t pair_bytes   = ((size_t)MAXE * MAXE * sizeof(float4) + 255) & ~(size_t)255;
    size_t packed_bytes = (((size_t)n_edges * sizeof(unsigned)) + 255) & ~(size_t)255;
    size_t part_bytes   = (size_t)C * SCAN_B2 * P2_CHUNK * sizeof(float);
    bool fast = (C >= 1) && (C <= MAXC) && (n_nodes <= ELEM_CAP) &&
                (n_elem >= 1) && (n_elem <= MAXE) &&
                (ws_size >= elem_bytes + pair_bytes + packed_bytes + part_bytes);

    if (fast) {
        unsigned char* elem     = (unsigned char*)d_ws;
        float4*        pair_tab = (float4*)((char*)d_ws + elem_bytes);
        unsigned*      packed   = (unsigned*)((char*)d_ws + elem_bytes + pair_bytes);
        float*         part     = (float*)((char*)d_ws + elem_bytes + pair_bytes + packed_bytes);

        zbl_prep_elem<<<(n_nodes + 255) / 256, 256, 0, stream>>>(
            node_attrs, elem, n_nodes, n_elem);
        zbl_prep_pairs<<<1, 256, 0, stream>>>(
            atomic_numbers, covalent_radii, pair_tab, n_elem);

        zbl_dense_lds<<<DN_BLOCKS, DN_THR, 0, stream>>>(
            x, edge_index, elem, pair_tab, packed, n_edges, n_elem, n_nodes);

        zbl_scan<<<C * SCAN_B2, SCAN_THR, 0, stream>>>(packed, part, n_edges);

        zbl_reduce<<<(n_nodes + 255) / 256, 256, 0, stream>>>(part, out, n_nodes);
        return;
    }

    // fallback: node table + plain device atomics
    float4* node_data = (float4*)d_ws;
    zbl_node_prep<<<(n_nodes + 255) / 256, 256, 0, stream>>>(
        node_attrs, atomic_numbers, covalent_radii, node_data,
        out, n_nodes, n_elem);
    zbl_edge_atomic<<<(n_edges + 255) / 256, 256, 0, stream>>>(
        x, edge_index, node_data, out, n_edges);
}

// Round 14
// 167.580 us; speedup vs baseline: 1.6010x; 1.0061x over previous
//
#include <hip/hip_runtime.h>

#define KE_CONST 14.3996454784255f

#define P2_SHIFT 15
#define P2_CHUNK 32768            // 128 KB LDS accumulator per chunk (scan)
#define SCAN_B2  64               // scan blocks per chunk
#define SCAN_THR 1024
#define MAXC     4
#define MAXE     16               // pair table up to 256 entries (4 KB LDS)
#define ELEM_CAP 131072           // 128 KB LDS elem table cap (dense)
#define DN_THR   1024
#define DN_BLOCKS 256

// ---------------- prep A: per-node element id (argmax over attrs) ----------------
__global__ void zbl_prep_elem(const float* __restrict__ node_attrs,
                              unsigned char* __restrict__ elem,
                              int n_nodes, int n_elem) {
    int n = blockIdx.x * blockDim.x + threadIdx.x;
    if (n >= n_nodes) return;
    const float* row = node_attrs + (size_t)n * n_elem;
    float best = row[0];
    int bi = 0;
    for (int i = 1; i < n_elem; ++i) {
        float v = row[i];
        if (v > best) { best = v; bi = i; }
    }
    elem[n] = (unsigned char)bi;
}

// ---------------- prep B: n_elem^2 pair table ----------------
__global__ void zbl_prep_pairs(const int* __restrict__ atomic_numbers,
                               const float* __restrict__ covalent_radii,
                               float4* __restrict__ pair_tab,
                               int n_elem) {
    int t = threadIdx.x;
    int np = n_elem * n_elem;
    if (t >= np) return;
    int eu = t / n_elem;
    int ev = t - eu * n_elem;
    int Zu = atomic_numbers[eu];
    int Zv = atomic_numbers[ev];
    float zu = (float)Zu, zv = (float)Zv;
    float inv_a = (__powf(zu, 0.3f) + __powf(zv, 0.3f)) * (1.0f / (0.4543f * 0.529f));
    float kezz  = 0.5f * KE_CONST * zu * zv;
    float rmax  = covalent_radii[Zu] + covalent_radii[Zv];
    pair_tab[t] = make_float4(inv_a, kezz, rmax, 1.0f / rmax);
}

// ---------------- per-edge e8m7 value from pair-table entry ----------------
__device__ __forceinline__ unsigned enc_val_p(float xv, const float4& p) {
    float t = xv * p.x;
    float phi = 0.1818f  * __expf(-3.2f    * t)
              + 0.5099f  * __expf(-0.9423f * t)
              + 0.2802f  * __expf(-0.4028f * t)
              + 0.02817f * __expf(-0.2016f * t);
    float rr = xv * p.w;
    float r2 = rr * rr;
    float r6 = r2 * r2 * r2;
    float env = 1.0f - 28.0f * r6 + 48.0f * r6 * rr - 21.0f * r6 * r2;
    float val = fmaxf(p.y * phi / xv * env, 0.0f);     // clamp r->1 cancellation negatives
    unsigned e = (__float_as_uint(val) + 0x8000u) >> 16;
    if (e > 0x7FFFu) e = 0x7FFFu;
    return (xv < p.z) ? e : 0u;
}

// ---------------- pass 1: dense streaming compute -> packed u32 per edge ----------------
__global__ __launch_bounds__(DN_THR)
void zbl_dense_lds(const float* __restrict__ x,
                   const int* __restrict__ ei,
                   const unsigned char* __restrict__ elem_g,
                   const float4* __restrict__ pair_tab,
                   unsigned* __restrict__ packed,
                   int n_edges, int n_elem, int n_nodes) {
    __shared__ __align__(16) unsigned char elem[ELEM_CAP];
    __shared__ float4 pt[MAXE * MAXE];

    int np = n_elem * n_elem;
    for (int i = threadIdx.x; i < np; i += DN_THR) pt[i] = pair_tab[i];
    int nwords = (n_nodes + 15) >> 4;
    const uint4* eg4 = (const uint4*)elem_g;
    uint4* el4 = (uint4*)elem;
    for (int i = threadIdx.x; i < nwords; i += DN_THR) el4[i] = eg4[i];
    __syncthreads();

    long long e0 = (((long long)blockIdx.x * n_edges) / DN_BLOCKS) & ~3LL;
    long long e1 = (blockIdx.x == DN_BLOCKS - 1)
                     ? (long long)n_edges
                     : ((((long long)(blockIdx.x + 1) * n_edges) / DN_BLOCKS) & ~3LL);
    long long vend = e1 & ~3LL;

    for (long long b = e0 + (long long)threadIdx.x * 4; b + 4 <= vend;
         b += (long long)DN_THR * 4) {
        int4   s4 = *(const int4*)(ei + b);
        int4   r4 = *(const int4*)(ei + n_edges + b);
        float4 x4 = *(const float4*)(x + b);
        unsigned es0 = elem[s4.x], es1 = elem[s4.y], es2 = elem[s4.z], es3 = elem[s4.w];
        unsigned er0 = elem[r4.x], er1 = elem[r4.y], er2 = elem[r4.z], er3 = elem[r4.w];
        float4 p0 = pt[es0 * n_elem + er0];
        float4 p1 = pt[es1 * n_elem + er1];
        float4 p2 = pt[es2 * n_elem + er2];
        float4 p3 = pt[es3 * n_elem + er3];
        uint4 o;
        o.x = ((unsigned)r4.x << 15) | enc_val_p(x4.x, p0);
        o.y = ((unsigned)r4.y << 15) | enc_val_p(x4.y, p1);
        o.z = ((unsigned)r4.z << 15) | enc_val_p(x4.z, p2);
        o.w = ((unsigned)r4.w << 15) | enc_val_p(x4.w, p3);
        *(uint4*)(packed + b) = o;
    }
    for (long long e = vend + threadIdx.x; e < e1; e += DN_THR) {
        int r = ei[n_edges + e];
        float4 p = pt[elem[ei[e]] * n_elem + elem[r]];
        packed[e] = ((unsigned)r << 15) | enc_val_p(x[e], p);
    }
}

// ---------------- pass 2: chunked scan, 4x-unrolled loads for MLP ----------------
// Round-13 scan had ONE uint4 load in flight per wave (latency-bound, 2.7 TB/s
// effective). Four independent wave-contiguous loads per iteration quadruple
// outstanding bytes.
#define SCAN_PROC(P)                                                            \
    if (((P).x >> 30) == c) atomicAdd(&acc[((P).x >> 15) & (P2_CHUNK - 1)],     \
                                      __uint_as_float(((P).x & 0x7FFFu) << 16));\
    if (((P).y >> 30) == c) atomicAdd(&acc[((P).y >> 15) & (P2_CHUNK - 1)],     \
                                      __uint_as_float(((P).y & 0x7FFFu) << 16));\
    if (((P).z >> 30) == c) atomicAdd(&acc[((P).z >> 15) & (P2_CHUNK - 1)],     \
                                      __uint_as_float(((P).z & 0x7FFFu) << 16));\
    if (((P).w >> 30) == c) atomicAdd(&acc[((P).w >> 15) & (P2_CHUNK - 1)],     \
                                      __uint_as_float(((P).w & 0x7FFFu) << 16));

__global__ __launch_bounds__(SCAN_THR)
void zbl_scan(const unsigned* __restrict__ packed,
              float* __restrict__ partial,
              int n_edges) {
    unsigned c = blockIdx.x >> 6;            // SCAN_B2 = 64
    int      j = blockIdx.x & (SCAN_B2 - 1);

    __shared__ __align__(16) float acc[P2_CHUNK];
    for (int i = threadIdx.x * 4; i < P2_CHUNK; i += SCAN_THR * 4)
        *(float4*)&acc[i] = make_float4(0.f, 0.f, 0.f, 0.f);
    __syncthreads();

    long long e0 = (((long long)j * n_edges) / SCAN_B2) & ~3LL;
    long long e1 = (j == SCAN_B2 - 1) ? (long long)n_edges
                                      : ((((long long)(j + 1) * n_edges) / SCAN_B2) & ~3LL);

    const long long T4 = (long long)SCAN_THR * 4;
    long long niter = (e1 - e0) / (T4 * 4);          // full 4x-unrolled iterations
    long long base = e0 + (long long)threadIdx.x * 4;
    for (long long i = 0; i < niter; ++i, base += T4 * 4) {
        uint4 q0 = *(const uint4*)(packed + base);
        uint4 q1 = *(const uint4*)(packed + base + T4);
        uint4 q2 = *(const uint4*)(packed + base + 2 * T4);
        uint4 q3 = *(const uint4*)(packed + base + 3 * T4);
        SCAN_PROC(q0);
        SCAN_PROC(q1);
        SCAN_PROC(q2);
        SCAN_PROC(q3);
    }
    // remainder: 4-wide then scalar
    long long rem0 = e0 + niter * T4 * 4;
    long long vend = e1 & ~3LL;
    for (long long b = rem0 + (long long)threadIdx.x * 4; b + 4 <= vend; b += T4) {
        uint4 p = *(const uint4*)(packed + b);
        SCAN_PROC(p);
    }
    for (long long e = vend + threadIdx.x; e < e1; e += SCAN_THR) {
        unsigned w = packed[e];
        if ((w >> 30) == c) atomicAdd(&acc[(w >> 15) & (P2_CHUNK - 1)],
                                      __uint_as_float((w & 0x7FFFu) << 16));
    }

    __syncthreads();
    float* pp = partial + (size_t)blockIdx.x * P2_CHUNK;
    for (int i = threadIdx.x * 4; i < P2_CHUNK; i += SCAN_THR * 4)
        *(float4*)(pp + i) = *(const float4*)&acc[i];
}

// ---------------- pass 3: reduce SCAN_B2 partials per node, overwrite out ----------------
__global__ void zbl_reduce(const float* __restrict__ partial,
                           float* __restrict__ out,
                           int n_nodes) {
    int i = blockIdx.x * blockDim.x + threadIdx.x;
    if (i >= n_nodes) return;
    int c  = i >> P2_SHIFT;
    int li = i & (P2_CHUNK - 1);
    const float* p = partial + ((size_t)c * SCAN_B2) * P2_CHUNK + li;
    float s0 = 0.f, s1 = 0.f, s2 = 0.f, s3 = 0.f;
    #pragma unroll
    for (int j = 0; j < SCAN_B2; j += 4) {
        s0 += p[(size_t)(j + 0) * P2_CHUNK];
        s1 += p[(size_t)(j + 1) * P2_CHUNK];
        s2 += p[(size_t)(j + 2) * P2_CHUNK];
        s3 += p[(size_t)(j + 3) * P2_CHUNK];
    }
    out[i] = (s0 + s1) + (s2 + s3);
}

// ================= fallback path: node float4 table + direct device atomics =================
__global__ void zbl_node_prep(const float* __restrict__ node_attrs,
                              const int* __restrict__ atomic_numbers,
                              const float* __restrict__ covalent_radii,
                              float4* __restrict__ node_data,
                              float* __restrict__ out_zero,
                              int n_nodes, int n_elem) {
    int n = blockIdx.x * blockDim.x + threadIdx.x;
    if (n >= n_nodes) return;
    const float* row = node_attrs + (size_t)n * n_elem;
    float best = row[0];
    int bi = 0;
    for (int i = 1; i < n_elem; ++i) {
        float v = row[i];
        if (v > best) { best = v; bi = i; }
    }
    int Z = atomic_numbers[bi];
    float zf = (float)Z;
    node_data[n] = make_float4(zf, __powf(zf, 0.3f), covalent_radii[Z], 0.0f);
    out_zero[n] = 0.0f;
}

__global__ void zbl_edge_atomic(const float* __restrict__ x,
                                const int* __restrict__ edge_index,
                                const float4* __restrict__ node_data,
                                float* __restrict__ out,
                                int n_edges) {
    int e = blockIdx.x * blockDim.x + threadIdx.x;
    if (e >= n_edges) return;
    int snd = edge_index[e];
    int r = edge_index[n_edges + e];
    float xv = x[e];
    float4 du = node_data[snd];
    float4 dv = node_data[r];
    float rmax = du.z + dv.z;
    if (xv >= rmax) return;
    const float inv_a_pref = 1.0f / (0.4543f * 0.529f);
    float t = xv * (du.y + dv.y) * inv_a_pref;
    float phi = 0.1818f  * __expf(-3.2f    * t)
              + 0.5099f  * __expf(-0.9423f * t)
              + 0.2802f  * __expf(-0.4028f * t)
              + 0.02817f * __expf(-0.2016f * t);
    float v = KE_CONST * du.x * dv.x * phi / xv;
    float rr = xv / rmax;
    float r2 = rr * rr;
    float r6 = r2 * r2 * r2;
    float env = 1.0f - 28.0f * r6 + 48.0f * r6 * rr - 21.0f * r6 * r2;
    atomicAdd(&out[r], 0.5f * v * env);
}

extern "C" void kernel_launch(void* const* d_in, const int* in_sizes, int n_in,
                              void* d_out, int out_size, void* d_ws, size_t ws_size,
                              hipStream_t stream) {
    const float* x              = (const float*)d_in[0];
    const float* node_attrs     = (const float*)d_in[1];
    const int*   edge_index     = (const int*)d_in[2];
    const int*   atomic_numbers = (const int*)d_in[3];
    const float* covalent_radii = (const float*)d_in[4];
    float* out = (float*)d_out;

    int n_edges = in_sizes[0];
    int n_elem  = in_sizes[3];
    int n_nodes = in_sizes[1] / n_elem;

    int C = (n_nodes + P2_CHUNK - 1) >> P2_SHIFT;
    size_t elem_bytes   = (((size_t)n_nodes) + 255) & ~(size_t)255;
    size_t pair_bytes   = ((size_t)MAXE * MAXE * sizeof(float4) + 255) & ~(size_t)255;
    size_t packed_bytes = (((size_t)n_edges * sizeof(unsigned)) + 255) & ~(size_t)255;
    size_t part_bytes   = (size_t)C * SCAN_B2 * P2_CHUNK * sizeof(float);
    bool fast = (C >= 1) && (C <= MAXC) && (n_nodes <= ELEM_CAP) &&
                (n_elem >= 1) && (n_elem <= MAXE) &&
                (ws_size >= elem_bytes + pair_bytes + packed_bytes + part_bytes);

    if (fast) {
        unsigned char* elem     = (unsigned char*)d_ws;
        float4*        pair_tab = (float4*)((char*)d_ws + elem_bytes);
        unsigned*      packed   = (unsigned*)((char*)d_ws + elem_bytes + pair_bytes);
        float*         part     = (float*)((char*)d_ws + elem_bytes + pair_bytes + packed_bytes);

        zbl_prep_elem<<<(n_nodes + 255) / 256, 256, 0, stream>>>(
            node_attrs, elem, n_nodes, n_elem);
        zbl_prep_pairs<<<1, 256, 0, stream>>>(
            atomic_numbers, covalent_radii, pair_tab, n_elem);

        zbl_dense_lds<<<DN_BLOCKS, DN_THR, 0, stream>>>(
            x, edge_index, elem, pair_tab, packed, n_edges, n_elem, n_nodes);

        zbl_scan<<<C * SCAN_B2, SCAN_THR, 0, stream>>>(packed, part, n_edges);

        zbl_reduce<<<(n_nodes + 255) / 256, 256, 0, stream>>>(part, out, n_nodes);
        return;
    }

    // fallback: node table + plain device atomics
    float4* node_data = (float4*)d_ws;
    zbl_node_prep<<<(n_nodes + 255) / 256, 256, 0, stream>>>(
        node_attrs, atomic_numbers, covalent_radii, node_data,
        out, n_nodes, n_elem);
    zbl_edge_atomic<<<(n_edges + 255) / 256, 256, 0, stream>>>(
        x, edge_index, node_data, out, n_edges);
}